// Round 1
// baseline (649.217 us; speedup 1.0000x reference)
//
#include <hip/hip_runtime.h>
#include <math.h>

// AFT attention: softmax(k) -> depthwise 31x31 conv on k and k*v (+ spatial-sum
// bias) -> sigmoid(q) * kv_c / (k_c + eps).
// bs=16, C=192, H=W=64. One workgroup per (b,c) channel image; everything
// fused in LDS, no workspace.

#define C_    192
#define HW_   4096
#define KS_   31
#define PAD_  15
#define PROW_ 94            // padded rows actually referenced (0..93)
#define PSTR_ 100           // padded row stride in floats; 100 % 32 == 4 -> spreads banks
#define NT_   256

// Each thread computes 16 contiguous outputs of one image row.
// Window: pad[y+dy][x0 .. x0+45]; weight row broadcast from LDS.
__device__ __forceinline__ void conv16(const float* __restrict__ sp,
                                       const float* __restrict__ swl,
                                       int y, int x0, float acc[16])
{
#pragma unroll 1
    for (int dy = 0; dy < KS_; ++dy) {
        float win[48];
        const float4* rp = reinterpret_cast<const float4*>(sp + (y + dy) * PSTR_ + x0);
#pragma unroll
        for (int i = 0; i < 12; ++i) {
            float4 v = rp[i];
            win[4*i+0] = v.x; win[4*i+1] = v.y; win[4*i+2] = v.z; win[4*i+3] = v.w;
        }
        float wr[32];
        const float4* wp = reinterpret_cast<const float4*>(swl + dy * 32);
#pragma unroll
        for (int i = 0; i < 8; ++i) {
            float4 v = wp[i];
            wr[4*i+0] = v.x; wr[4*i+1] = v.y; wr[4*i+2] = v.z; wr[4*i+3] = v.w;
        }
#pragma unroll
        for (int dx = 0; dx < KS_; ++dx) {
#pragma unroll
            for (int j = 0; j < 16; ++j) {
                acc[j] = fmaf(wr[dx], win[dx + j], acc[j]);
            }
        }
    }
}

__global__ __launch_bounds__(NT_, 3)
void aft_fused(const float* __restrict__ qkv,
               const float* __restrict__ wts,
               float* __restrict__ out)
{
    __shared__ float pad[PROW_ * PSTR_];   // 37,600 B zero-padded image
    __shared__ float wl[KS_ * 32];         //  3,968 B expm1(weights), row stride 32
    __shared__ float red[16];

    const int bc = blockIdx.x;
    const int b  = bc / C_;
    const int c  = bc - b * C_;

    const float* qrow = qkv + ((size_t)b * (3 * C_) + c) * HW_;
    const float* krow = qrow + (size_t)C_ * HW_;
    const float* vrow = qrow + (size_t)(2 * C_) * HW_;
    float*       orow = out + ((size_t)b * C_ + c) * HW_;

    const int t    = threadIdx.x;
    const int y    = t >> 2;               // output row 0..63
    const int x0   = (t & 3) << 4;         // output col block {0,16,32,48}
    const int lane = t & 63;
    const int wid  = t >> 6;
    const int f4b  = y * 16 + (x0 >> 2);   // float4 index of this thread's 16 px

    // ---- phase 0: zero padded buffer; load + expm1 weights ----
    for (int i = t; i < PROW_ * PSTR_; i += NT_) pad[i] = 0.f;
    for (int i = t; i < KS_ * KS_; i += NT_)
        wl[(i / KS_) * 32 + (i % KS_)] = expm1f(wts[(size_t)c * (KS_ * KS_) + i]);

    // ---- softmax over the 4096-pixel k row ----
    float kreg[16];
    float m = -3.0e38f;
#pragma unroll
    for (int j = 0; j < 4; ++j) {
        float4 v = reinterpret_cast<const float4*>(krow)[f4b + j];
        kreg[4*j+0] = v.x; kreg[4*j+1] = v.y; kreg[4*j+2] = v.z; kreg[4*j+3] = v.w;
        m = fmaxf(m, fmaxf(fmaxf(v.x, v.y), fmaxf(v.z, v.w)));
    }
#pragma unroll
    for (int s = 32; s > 0; s >>= 1) m = fmaxf(m, __shfl_xor(m, s));
    if (lane == 0) red[wid] = m;
    __syncthreads();
    m = fmaxf(fmaxf(red[0], red[1]), fmaxf(red[2], red[3]));

    float lsum = 0.f;
#pragma unroll
    for (int j = 0; j < 16; ++j) { kreg[j] = __expf(kreg[j] - m); lsum += kreg[j]; }
#pragma unroll
    for (int s = 32; s > 0; s >>= 1) lsum += __shfl_xor(lsum, s);
    if (lane == 0) red[8 + wid] = lsum;
    __syncthreads();
    const float inv = 1.f / (red[8] + red[9] + red[10] + red[11]);

    float* prow = pad + (PAD_ + y) * PSTR_ + PAD_ + x0;
#pragma unroll
    for (int j = 0; j < 16; ++j) { kreg[j] *= inv; prow[j] = kreg[j]; }
    __syncthreads();                       // pad now holds softmax(k), zeros outside

    // ---- conv pass 1: k ----
    float acck[16];
#pragma unroll
    for (int j = 0; j < 16; ++j) acck[j] = 0.f;
    conv16(pad, wl, y, x0, acck);
    __syncthreads();                       // all conv-1 reads done before overwrite

    // ---- kv = k*v into the same buffer; block sums of k and kv ----
    float lsk = 0.f, lskv = 0.f;
#pragma unroll
    for (int j = 0; j < 4; ++j) {
        float4 v = reinterpret_cast<const float4*>(vrow)[f4b + j];
        float a0 = kreg[4*j+0] * v.x;
        float a1 = kreg[4*j+1] * v.y;
        float a2 = kreg[4*j+2] * v.z;
        float a3 = kreg[4*j+3] * v.w;
        prow[4*j+0] = a0; prow[4*j+1] = a1; prow[4*j+2] = a2; prow[4*j+3] = a3;
        lskv += (a0 + a1) + (a2 + a3);
        lsk  += (kreg[4*j+0] + kreg[4*j+1]) + (kreg[4*j+2] + kreg[4*j+3]);
    }
#pragma unroll
    for (int s = 32; s > 0; s >>= 1) {
        lsk  += __shfl_xor(lsk,  s);
        lskv += __shfl_xor(lskv, s);
    }
    if (lane == 0) { red[wid] = lsk; red[8 + wid] = lskv; }
    __syncthreads();                       // kv writes + sums visible
    const float sumk  = red[0] + red[1] + red[2] + red[3];
    const float sumkv = red[8] + red[9] + red[10] + red[11];

    // ---- conv pass 2: kv ----
    float acckv[16];
#pragma unroll
    for (int j = 0; j < 16; ++j) acckv[j] = 0.f;
    conv16(pad, wl, y, x0, acckv);

    // ---- combine and store ----
#pragma unroll
    for (int j = 0; j < 4; ++j) {
        float4 qv = reinterpret_cast<const float4*>(qrow)[f4b + j];
        float4 o;
        {
            float sig = 1.f / (1.f + __expf(-qv.x));
            o.x = sig * (acckv[4*j+0] + sumkv) / (acck[4*j+0] + sumk + 1e-8f);
        }
        {
            float sig = 1.f / (1.f + __expf(-qv.y));
            o.y = sig * (acckv[4*j+1] + sumkv) / (acck[4*j+1] + sumk + 1e-8f);
        }
        {
            float sig = 1.f / (1.f + __expf(-qv.z));
            o.z = sig * (acckv[4*j+2] + sumkv) / (acck[4*j+2] + sumk + 1e-8f);
        }
        {
            float sig = 1.f / (1.f + __expf(-qv.w));
            o.w = sig * (acckv[4*j+3] + sumkv) / (acck[4*j+3] + sumk + 1e-8f);
        }
        reinterpret_cast<float4*>(orow)[f4b + j] = o;
    }
}

extern "C" void kernel_launch(void* const* d_in, const int* in_sizes, int n_in,
                              void* d_out, int out_size, void* d_ws, size_t ws_size,
                              hipStream_t stream)
{
    const float* qkv = (const float*)d_in[0];   // (16, 576, 4096) fp32
    const float* wts = (const float*)d_in[1];   // (192, 1, 31, 31) fp32
    float* out       = (float*)d_out;           // (16, 192, 4096) fp32
    (void)in_sizes; (void)n_in; (void)d_ws; (void)ws_size; (void)out_size;

    const int bs = 16;
    dim3 grid(bs * C_);
    dim3 block(NT_);
    aft_fused<<<grid, block, 0, stream>>>(qkv, wts, out);
}

// Round 2
// 538.335 us; speedup vs baseline: 1.2060x; 1.2060x over previous
//
#include <hip/hip_runtime.h>
#include <math.h>

// AFT attention fused kernel, round 2: dy-paired f16 dot2 convolution.
// softmax(k) -> depthwise 31x31 conv on k and k*v (+ spatial-sum bias)
// -> sigmoid(q)*kv_c/(k_c+eps).  bs=16, C=192, H=W=64.
// One workgroup per (b,c). Image lives in LDS as u32 pair-rows:
// P[r][x] = (f16 img[r][x], f16 img[r+1][x]) so v_dot2_f32_f16 consumes
// (w[2p][dx], w[2p+1][dx]) . (img[y+2p][x+dx], img[y+2p+1][x+dx]) with
// zero repacking. Accumulation in f32.

#define C_     192
#define HW_    4096
#define KS_    31
#define PAD_   15
#define PROWS_ 94           // pair rows 0..93 (covers img rows 0..94)
#define PSTR_  100          // u32 row stride; 100 % 32 == 4 -> 8-phase-minimal b128
#define NT_    256

typedef _Float16 half2_t __attribute__((ext_vector_type(2)));

__device__ __forceinline__ float fdot2(unsigned int a, unsigned int b, float c) {
#if __has_builtin(__builtin_amdgcn_fdot2)
    return __builtin_amdgcn_fdot2(__builtin_bit_cast(half2_t, a),
                                  __builtin_bit_cast(half2_t, b), c, false);
#else
    half2_t ha = __builtin_bit_cast(half2_t, a);
    half2_t hb = __builtin_bit_cast(half2_t, b);
    return fmaf((float)ha.y, (float)hb.y, fmaf((float)ha.x, (float)hb.x, c));
#endif
}

// 16 contiguous outputs of one row; 16 pair-row steps; dx in 4 chunks of 8
// (taps 31..31 padded with zero weights -> uniform chunks, low reg pressure).
__device__ __forceinline__ void conv16p(const unsigned int* __restrict__ P,
                                        const unsigned int* __restrict__ WL,
                                        int yo, int x0c, float acc[16])
{
#pragma unroll 1
    for (int p = 0; p < 16; ++p) {
        unsigned int win[48];
        const uint4* rp = reinterpret_cast<const uint4*>(P + (yo + 2 * p) * PSTR_ + x0c);
#pragma unroll
        for (int i = 0; i < 12; ++i) {
            uint4 v = rp[i];
            win[4*i+0] = v.x; win[4*i+1] = v.y; win[4*i+2] = v.z; win[4*i+3] = v.w;
        }
        const uint4* wp = reinterpret_cast<const uint4*>(WL + p * 32);
#pragma unroll
        for (int ch = 0; ch < 4; ++ch) {
            uint4 w0 = wp[2*ch + 0];
            uint4 w1 = wp[2*ch + 1];
            unsigned int wr[8] = {w0.x, w0.y, w0.z, w0.w, w1.x, w1.y, w1.z, w1.w};
#pragma unroll
            for (int dxl = 0; dxl < 8; ++dxl) {
                const int dx = ch * 8 + dxl;
#pragma unroll
                for (int j = 0; j < 16; ++j)
                    acc[j] = fdot2(wr[dxl], win[dx + j], acc[j]);
            }
        }
    }
}

__global__ __launch_bounds__(NT_, 4)
void aft_fused(const float* __restrict__ qkv,
               const float* __restrict__ wts,
               float* __restrict__ out)
{
    __shared__ unsigned int P[PROWS_ * PSTR_];   // 37,600 B pair-row f16 image
    __shared__ unsigned int WL[16 * 32];         //  2,048 B packed weight pairs
    __shared__ float red[16];

    const int bc = blockIdx.x;
    const int b  = bc / C_;
    const int c  = bc - b * C_;

    const float* qrow = qkv + ((size_t)b * (3 * C_) + c) * HW_;
    const float* krow = qrow + (size_t)C_ * HW_;
    const float* vrow = qrow + (size_t)(2 * C_) * HW_;
    float*       orow = out + ((size_t)b * C_ + c) * HW_;

    const int t    = threadIdx.x;
    const int yo   = t >> 2;              // output row 0..63
    const int x0c  = (t & 3) << 4;        // output col block {0,16,32,48}
    const int lane = t & 63;
    const int wid  = t >> 6;
    const int f4b  = yo * 16 + (x0c >> 2);

    // ---- zero-fill pair image; build packed expm1 weight pairs ----
    uint4* P4 = reinterpret_cast<uint4*>(P);
    for (int i = t; i < (PROWS_ * PSTR_) / 4; i += NT_)
        P4[i] = make_uint4(0u, 0u, 0u, 0u);
    for (int i = t; i < 512; i += NT_) {
        const int p = i >> 5, dx = i & 31;
        float wa = 0.f, wb = 0.f;
        if (dx < KS_) {
            wa = expm1f(wts[(size_t)c * (KS_ * KS_) + (2 * p) * KS_ + dx]);
            if (2 * p + 1 < KS_)
                wb = expm1f(wts[(size_t)c * (KS_ * KS_) + (2 * p + 1) * KS_ + dx]);
        }
        half2_t h; h.x = (_Float16)wa; h.y = (_Float16)wb;
        WL[i] = __builtin_bit_cast(unsigned int, h);
    }

    // ---- softmax over the 4096-pixel k row (f32) ----
    float kreg[16];
    float m = -3.0e38f;
#pragma unroll
    for (int j = 0; j < 4; ++j) {
        float4 v = reinterpret_cast<const float4*>(krow)[f4b + j];
        kreg[4*j+0] = v.x; kreg[4*j+1] = v.y; kreg[4*j+2] = v.z; kreg[4*j+3] = v.w;
        m = fmaxf(m, fmaxf(fmaxf(v.x, v.y), fmaxf(v.z, v.w)));
    }
#pragma unroll
    for (int s = 32; s > 0; s >>= 1) m = fmaxf(m, __shfl_xor(m, s));
    if (lane == 0) red[wid] = m;
    __syncthreads();                       // also fences zero-fill + weights
    m = fmaxf(fmaxf(red[0], red[1]), fmaxf(red[2], red[3]));

    float lsum = 0.f;
#pragma unroll
    for (int j = 0; j < 16; ++j) { kreg[j] = __expf(kreg[j] - m); lsum += kreg[j]; }
#pragma unroll
    for (int s = 32; s > 0; s >>= 1) lsum += __shfl_xor(lsum, s);
    if (lane == 0) red[8 + wid] = lsum;
    __syncthreads();
    const float inv = 1.f / (red[8] + red[9] + red[10] + red[11]);

    // normalize; keep a packed f16 copy for the kv pass (8 regs, not 16)
    unsigned int kh[8];
#pragma unroll
    for (int j = 0; j < 8; ++j) {
        kreg[2*j]   *= inv;
        kreg[2*j+1] *= inv;
        half2_t h; h.x = (_Float16)kreg[2*j]; h.y = (_Float16)kreg[2*j+1];
        kh[j] = __builtin_bit_cast(unsigned int, h);
    }

    // write k into pair image: P[rp][xp].lo = v, P[rp-1][xp].hi = v
    unsigned short* P16 = reinterpret_cast<unsigned short*>(P);
    const int rp  = PAD_ + yo;
    const int xp0 = PAD_ + x0c;
#pragma unroll
    for (int j = 0; j < 8; ++j) {
        const unsigned int u = kh[j];
        const int xa = xp0 + 2*j, xb2 = xp0 + 2*j + 1;
        P16[(rp * PSTR_ + xa) * 2]           = (unsigned short)(u & 0xffffu);
        P16[(rp * PSTR_ + xb2) * 2]          = (unsigned short)(u >> 16);
        P16[((rp - 1) * PSTR_ + xa) * 2 + 1] = (unsigned short)(u & 0xffffu);
        P16[((rp - 1) * PSTR_ + xb2) * 2 + 1] = (unsigned short)(u >> 16);
    }
    __syncthreads();                       // image ready

    // ---- conv pass 1: k ----
    float acck[16];
#pragma unroll
    for (int j = 0; j < 16; ++j) acck[j] = 0.f;
    conv16p(P, WL, yo, x0c, acck);
    __syncthreads();                       // conv-1 reads done before overwrite

    // ---- kv = f16(k)*v into the same image; block sum of kv ----
    float lskv = 0.f;
#pragma unroll
    for (int j = 0; j < 4; ++j) {
        float4 v4 = reinterpret_cast<const float4*>(vrow)[f4b + j];
        half2_t h0 = __builtin_bit_cast(half2_t, kh[2*j]);
        half2_t h1 = __builtin_bit_cast(half2_t, kh[2*j+1]);
        float a0 = (float)h0.x * v4.x;
        float a1 = (float)h0.y * v4.y;
        float a2 = (float)h1.x * v4.z;
        float a3 = (float)h1.y * v4.w;
        lskv += (a0 + a1) + (a2 + a3);
        half2_t o0; o0.x = (_Float16)a0; o0.y = (_Float16)a1;
        half2_t o1; o1.x = (_Float16)a2; o1.y = (_Float16)a3;
        const unsigned int u0 = __builtin_bit_cast(unsigned int, o0);
        const unsigned int u1 = __builtin_bit_cast(unsigned int, o1);
        const int x0j = xp0 + 4*j;
        P16[(rp * PSTR_ + x0j + 0) * 2]           = (unsigned short)(u0 & 0xffffu);
        P16[(rp * PSTR_ + x0j + 1) * 2]           = (unsigned short)(u0 >> 16);
        P16[(rp * PSTR_ + x0j + 2) * 2]           = (unsigned short)(u1 & 0xffffu);
        P16[(rp * PSTR_ + x0j + 3) * 2]           = (unsigned short)(u1 >> 16);
        P16[((rp - 1) * PSTR_ + x0j + 0) * 2 + 1] = (unsigned short)(u0 & 0xffffu);
        P16[((rp - 1) * PSTR_ + x0j + 1) * 2 + 1] = (unsigned short)(u0 >> 16);
        P16[((rp - 1) * PSTR_ + x0j + 2) * 2 + 1] = (unsigned short)(u1 & 0xffffu);
        P16[((rp - 1) * PSTR_ + x0j + 3) * 2 + 1] = (unsigned short)(u1 >> 16);
    }
#pragma unroll
    for (int s = 32; s > 0; s >>= 1) lskv += __shfl_xor(lskv, s);
    if (lane == 0) red[wid] = lskv;
    __syncthreads();                       // kv image + partial sums visible
    const float sumkv = red[0] + red[1] + red[2] + red[3];
    const float sumk  = 1.0f;              // softmax sums to 1 (f32-exact enough)

    // ---- conv pass 2: kv ----
    float acckv[16];
#pragma unroll
    for (int j = 0; j < 16; ++j) acckv[j] = 0.f;
    conv16p(P, WL, yo, x0c, acckv);

    // ---- combine and store ----
#pragma unroll
    for (int j = 0; j < 4; ++j) {
        float4 qv = reinterpret_cast<const float4*>(qrow)[f4b + j];
        float4 o;
        o.x = (acckv[4*j+0] + sumkv) / ((acck[4*j+0] + sumk + 1e-8f) * (1.f + __expf(-qv.x)));
        o.y = (acckv[4*j+1] + sumkv) / ((acck[4*j+1] + sumk + 1e-8f) * (1.f + __expf(-qv.y)));
        o.z = (acckv[4*j+2] + sumkv) / ((acck[4*j+2] + sumk + 1e-8f) * (1.f + __expf(-qv.z)));
        o.w = (acckv[4*j+3] + sumkv) / ((acck[4*j+3] + sumk + 1e-8f) * (1.f + __expf(-qv.w)));
        reinterpret_cast<float4*>(orow)[f4b + j] = o;
    }
}

extern "C" void kernel_launch(void* const* d_in, const int* in_sizes, int n_in,
                              void* d_out, int out_size, void* d_ws, size_t ws_size,
                              hipStream_t stream)
{
    const float* qkv = (const float*)d_in[0];   // (16, 576, 4096) fp32
    const float* wts = (const float*)d_in[1];   // (192, 1, 31, 31) fp32
    float* out       = (float*)d_out;           // (16, 192, 4096) fp32
    (void)in_sizes; (void)n_in; (void)d_ws; (void)ws_size; (void)out_size;

    aft_fused<<<dim3(16 * C_), dim3(NT_), 0, stream>>>(qkv, wts, out);
}

// Round 3
// 299.497 us; speedup vs baseline: 2.1677x; 1.7975x over previous
//
#include <hip/hip_runtime.h>
#include <math.h>

// AFT attention, round 3: MFMA Toeplitz-band depthwise conv.
// Per dy, the 31x31 depthwise conv is a banded matmul:
//   Out[y][x] += sum_kc Ipad[ybase+y+dy][xbase+kc] * W[dy][kc - xm - 1]
// A = image rows (contiguous f16 from LDS), B = weight-row Toeplitz
// (precomputed f16 pairs in LDS), D = 32x32 output tile via
// v_mfma_f32_32x32x16_f16. One block (128 thr = 2 waves) per (b,c);
// wave w owns output rows [32w, 32w+32), both 32-wide x tiles.

#define C_     192
#define HW_    4096
#define KS_    31
#define IROWS_ 94
#define ISTR_  100   // f16 stride: 50 dwords -> b64 reads bijective over bank pairs
#define WCOLS_ 96    // u32 pair-columns per weight Toeplitz row
#define NT_    128

typedef _Float16 f16;
typedef _Float16 f16x4 __attribute__((ext_vector_type(4)));
typedef _Float16 f16x8 __attribute__((ext_vector_type(8)));
typedef float    f32x16 __attribute__((ext_vector_type(16)));

// Fragment mapping (gfx950): lane l, f16 slot j ->
//   A: row = l&31, k = 4*(l>>5) + (j&3) + 8*(j>>2)
//   B: col = l&31, k = same
//   D: col = l&31, row = (r&3) + 8*(r>>2) + 4*(l>>5)
__device__ __forceinline__ void conv_pass(const f16* __restrict__ img,
                                          const unsigned int* __restrict__ wp,
                                          int lane, int ybase,
                                          f32x16* acc0, f32x16* acc1)
{
    const int l5  = lane >> 5;
    const int l31 = lane & 31;
    int aoff = (ybase + l31) * ISTR_ + 4 * l5;          // f16 index
    const unsigned int* bp0 = wp + (32 + 4 * l5 - l31); // dword index, >= 1
#pragma unroll 1
    for (int dy = 0; dy < KS_; ++dy) {
        f16x8 A[6];
        const f16* ap = img + aoff;
#pragma unroll
        for (int cc = 0; cc < 6; ++cc) {
            f16x4 lo = *(const f16x4*)(ap + cc * 16);       // k 0..3 of half
            f16x4 hi = *(const f16x4*)(ap + cc * 16 + 8);   // k 8..11 of half
            A[cc] = __builtin_shufflevector(lo, hi, 0, 1, 2, 3, 4, 5, 6, 7);
        }
        const unsigned int* bp = bp0 + dy * WCOLS_;
#pragma unroll
        for (int kc = 0; kc < 4; ++kc) {
            // pairs at w-indices {base-1,base},{base+1,base+2},{base+7,base+8},{base+9,base+10}
            uint4 bw;
            bw.x = bp[kc * 16 + 0];
            bw.y = bp[kc * 16 + 2];
            bw.z = bp[kc * 16 + 8];
            bw.w = bp[kc * 16 + 10];
            f16x8 B = __builtin_bit_cast(f16x8, bw);
            *acc0 = __builtin_amdgcn_mfma_f32_32x32x16_f16(A[kc],     B, *acc0, 0, 0, 0);
            *acc1 = __builtin_amdgcn_mfma_f32_32x32x16_f16(A[kc + 2], B, *acc1, 0, 0, 0);
        }
        aoff += ISTR_;
    }
}

__global__ __launch_bounds__(NT_, 2)
void aft_mfma(const float* __restrict__ qkv,
              const float* __restrict__ wts,
              float* __restrict__ out)
{
    __shared__ __align__(16) f16 IMG[IROWS_ * ISTR_];   // 18,800 B padded image
    __shared__ unsigned int WP[KS_ * WCOLS_];           // 11,904 B Toeplitz pairs
    __shared__ float red[8];

    const int bc = blockIdx.x;
    const int b  = bc / C_;
    const int c  = bc - b * C_;
    const float* qrow = qkv + ((size_t)b * (3 * C_) + c) * HW_;
    const float* krow = qrow + (size_t)C_ * HW_;
    const float* vrow = qrow + (size_t)(2 * C_) * HW_;
    float*       orow = out + ((size_t)b * C_ + c) * HW_;

    const int t = threadIdx.x, lane = t & 63, wid = t >> 6;

    // ---- zero image; build weight Toeplitz pairs WP[dy][c] = (w(c-33), w(c-32)) ----
    unsigned int* IMGu = (unsigned int*)IMG;
    for (int i = t; i < (IROWS_ * ISTR_) / 2; i += NT_) IMGu[i] = 0u;
    const float* wch = wts + (size_t)c * (KS_ * KS_);
    for (int i = t; i < KS_ * WCOLS_; i += NT_) {
        const int dy = i / WCOLS_, cw = i - dy * WCOLS_;
        const int d0 = cw - 33, d1 = cw - 32;
        const float w0 = (d0 >= 0 && d0 < KS_) ? expm1f(wch[dy * KS_ + d0]) : 0.f;
        const float w1 = (d1 >= 0 && d1 < KS_) ? expm1f(wch[dy * KS_ + d1]) : 0.f;
        union { unsigned int u; f16 h[2]; } pk;
        pk.h[0] = (f16)w0; pk.h[1] = (f16)w1;
        WP[i] = pk.u;
    }

    // ---- softmax over 4096 k values (unnormalized exp; fold Z into epilogue) ----
    float kvv[32];
    float pm = -3.0e38f;
#pragma unroll
    for (int i = 0; i < 8; ++i) {
        float4 v = ((const float4*)krow)[t + NT_ * i];
        kvv[4*i+0] = v.x; kvv[4*i+1] = v.y; kvv[4*i+2] = v.z; kvv[4*i+3] = v.w;
        pm = fmaxf(pm, fmaxf(fmaxf(v.x, v.y), fmaxf(v.z, v.w)));
    }
#pragma unroll
    for (int s = 32; s; s >>= 1) pm = fmaxf(pm, __shfl_xor(pm, s));
    if (lane == 0) red[wid] = pm;
    __syncthreads();                       // also fences zero-fill + WP build
    const float m = fmaxf(red[0], red[1]);

    const int ry = t >> 4;                 // image row component (0..7)
    const int rx = (t & 15) * 4;           // image col component
    float ps = 0.f;
#pragma unroll
    for (int i = 0; i < 8; ++i) {
        f16x4 h;
#pragma unroll
        for (int e = 0; e < 4; ++e) {
            float ev = __expf(kvv[4*i+e] - m);
            ps += ev;
            h[e] = (f16)ev;
        }
        *(f16x4*)(&IMG[(ry + 8 * i + 15) * ISTR_ + rx + 16]) = h;
    }
#pragma unroll
    for (int s = 32; s; s >>= 1) ps += __shfl_xor(ps, s);
    if (lane == 0) red[2 + wid] = ps;
    __syncthreads();                       // image(e) + Z ready
    const float Z = red[2] + red[3];

    // ---- conv pass 1: e = exp(k - m) ----
    f32x16 accA0, accA1;
#pragma unroll
    for (int r = 0; r < 16; ++r) { accA0[r] = 0.f; accA1[r] = 0.f; }
    conv_pass(IMG, WP, lane, 32 * wid, &accA0, &accA1);
    __syncthreads();                       // all conv-1 reads complete

    // ---- kv = e * v into same image; block sum of kv ----
    float skv = 0.f;
#pragma unroll
    for (int i = 0; i < 8; ++i) {
        float4 v = ((const float4*)vrow)[t + NT_ * i];
        f16* pp = &IMG[(ry + 8 * i + 15) * ISTR_ + rx + 16];
        f16x4 h = *(f16x4*)pp;
        float a0 = (float)h[0] * v.x;
        float a1 = (float)h[1] * v.y;
        float a2 = (float)h[2] * v.z;
        float a3 = (float)h[3] * v.w;
        skv += (a0 + a1) + (a2 + a3);
        h[0] = (f16)a0; h[1] = (f16)a1; h[2] = (f16)a2; h[3] = (f16)a3;
        *(f16x4*)pp = h;
    }
#pragma unroll
    for (int s = 32; s; s >>= 1) skv += __shfl_xor(skv, s);
    if (lane == 0) red[4 + wid] = skv;
    __syncthreads();                       // kv image + sums visible
    const float sumkv = red[4] + red[5];

    // ---- conv pass 2: kv ----
    f32x16 accB0, accB1;
#pragma unroll
    for (int r = 0; r < 16; ++r) { accB0[r] = 0.f; accB1[r] = 0.f; }
    conv_pass(IMG, WP, lane, 32 * wid, &accB0, &accB1);

    // ---- epilogue: out = sig(q) * (kv_c + sumkv) / (k_c + Z) ----
    const float l5f = (float)0; (void)l5f;
    const int yb = 32 * wid + 4 * (lane >> 5);
    const int l31 = lane & 31;
#pragma unroll
    for (int tt = 0; tt < 2; ++tt) {
        const f32x16& ka = tt ? accA1 : accA0;
        const f32x16& va = tt ? accB1 : accB0;
        const int x = 32 * tt + l31;
#pragma unroll
        for (int r = 0; r < 16; ++r) {
            const int y = yb + (r & 3) + 8 * (r >> 2);
            const int idx = y * 64 + x;
            const float qv = qrow[idx];
            const float den = (ka[r] + Z + Z * 1e-8f) * (1.f + __expf(-qv));
            orow[idx] = (va[r] + sumkv) * __builtin_amdgcn_rcpf(den);
        }
    }
}

extern "C" void kernel_launch(void* const* d_in, const int* in_sizes, int n_in,
                              void* d_out, int out_size, void* d_ws, size_t ws_size,
                              hipStream_t stream)
{
    const float* qkv = (const float*)d_in[0];   // (16, 576, 4096) fp32
    const float* wts = (const float*)d_in[1];   // (192, 1, 31, 31) fp32
    float* out       = (float*)d_out;           // (16, 192, 4096) fp32
    (void)in_sizes; (void)n_in; (void)d_ws; (void)ws_size; (void)out_size;

    aft_mfma<<<dim3(16 * C_), dim3(NT_), 0, stream>>>(qkv, wts, out);
}